// Round 13
// baseline (627.164 us; speedup 1.0000x reference)
//
#include <hip/hip_runtime.h>

// Problem constants
#define NB 128      // batch
#define NM 64       // sensors
#define NT 128      // snapshots
#define NG 2048     // gridpoints
#define NH 32       // hidden
// VAR_NOISE = 0.1f

// ---------------------------------------------------------------------------
// Workspace layout (floats):
//  D   [128*64*64]   off 0
//  P0  [128*64*64]   off 524288   (cov partial q0; k_invpost overwrites with S)
//  P1  [128*64*64]   off 1048576  (cov partial q1; k_invpost overwrites with M)
//  P2  [128*64*64]   off 1572864  (cov partial q2)
//  P3  [128*64*64]   off 2097152  (cov partial q3)
//  T1  [128*2048]    off 2621440
//  T2  [128*2048]    off 2883584
//  gA  [128*2048]    off 3145728
//  gB  [128*2048]    off 3407872
// ---------------------------------------------------------------------------

__global__ __launch_bounds__(256) void k_init(float* __restrict__ g) {
    g[blockIdx.x * 256 + threadIdx.x] = 1.0f;
}

// D[b] = data[b] * data[b]^T / NT    (once per call; data constant)
__global__ __launch_bounds__(256) void k_D(const float* __restrict__ data,
                                           float* __restrict__ D) {
    __shared__ float sd[64 * 133];
    int b = blockIdx.x, t = threadIdx.x;
    const float* db = data + (size_t)b * 8192;
    for (int idx = t; idx < 8192; idx += 256)
        sd[(idx >> 7) * 133 + (idx & 127)] = db[idx];
    __syncthreads();
    int i0 = (t & 15) * 4, j0 = (t >> 4) * 4;
    float acc[4][4];
#pragma unroll
    for (int r = 0; r < 4; ++r)
#pragma unroll
        for (int c = 0; c < 4; ++c) acc[r][c] = 0.f;
    for (int tt = 0; tt < 128; ++tt) {
        float av[4], bv[4];
#pragma unroll
        for (int r = 0; r < 4; ++r) av[r] = sd[(i0 + r) * 133 + tt];
#pragma unroll
        for (int c = 0; c < 4; ++c) bv[c] = sd[(j0 + c) * 133 + tt];
#pragma unroll
        for (int r = 0; r < 4; ++r)
#pragma unroll
            for (int c = 0; c < 4; ++c) acc[r][c] += av[r] * bv[c];
    }
    float* Db = D + (size_t)b * 4096;
#pragma unroll
    for (int r = 0; r < 4; ++r)
#pragma unroll
        for (int c = 0; c < 4; ++c)
            Db[(i0 + r) * 64 + j0 + c] = acc[r][c] * (1.0f / 128.0f);
}

// Partial covariance: block (b, quarter q) accumulates over 512 g's.
__global__ __launch_bounds__(256) void k_cov(const float* __restrict__ A,
                                             const float* __restrict__ g,
                                             float* __restrict__ p0,
                                             float* __restrict__ p1,
                                             float* __restrict__ p2,
                                             float* __restrict__ p3) {
    int b = blockIdx.x >> 2, q = blockIdx.x & 3, t = threadIdx.x;
    int goff = q * 512;
    __shared__ float sA[32 * 64];    // [gg][m]
    __shared__ float sAg[32 * 64];   // scaled by gamma
    __shared__ float sg[512];
    for (int idx = t; idx < 512; idx += 256)
        sg[idx] = g[(size_t)b * NG + goff + idx];
    float acc[4][4];
#pragma unroll
    for (int r = 0; r < 4; ++r)
#pragma unroll
        for (int c = 0; c < 4; ++c) acc[r][c] = 0.f;
    int i0 = (t & 15) * 4, j0 = (t >> 4) * 4;
    int m = t >> 2, gs = (t & 3) * 8;
    __syncthreads();
    for (int ch = 0; ch < 16; ++ch) {
        const float* Ar = A + (size_t)m * NG + goff + ch * 32 + gs;
        float4 v0 = *(const float4*)Ar;
        float4 v1 = *(const float4*)(Ar + 4);
        __syncthreads();
        sA[(gs + 0) * 64 + m] = v0.x; sAg[(gs + 0) * 64 + m] = v0.x * sg[ch * 32 + gs + 0];
        sA[(gs + 1) * 64 + m] = v0.y; sAg[(gs + 1) * 64 + m] = v0.y * sg[ch * 32 + gs + 1];
        sA[(gs + 2) * 64 + m] = v0.z; sAg[(gs + 2) * 64 + m] = v0.z * sg[ch * 32 + gs + 2];
        sA[(gs + 3) * 64 + m] = v0.w; sAg[(gs + 3) * 64 + m] = v0.w * sg[ch * 32 + gs + 3];
        sA[(gs + 4) * 64 + m] = v1.x; sAg[(gs + 4) * 64 + m] = v1.x * sg[ch * 32 + gs + 4];
        sA[(gs + 5) * 64 + m] = v1.y; sAg[(gs + 5) * 64 + m] = v1.y * sg[ch * 32 + gs + 5];
        sA[(gs + 6) * 64 + m] = v1.z; sAg[(gs + 6) * 64 + m] = v1.z * sg[ch * 32 + gs + 6];
        sA[(gs + 7) * 64 + m] = v1.w; sAg[(gs + 7) * 64 + m] = v1.w * sg[ch * 32 + gs + 7];
        __syncthreads();
#pragma unroll
        for (int gg = 0; gg < 32; ++gg) {
            float4 av = *(const float4*)&sAg[gg * 64 + i0];
            float4 bv = *(const float4*)&sA[gg * 64 + j0];
            acc[0][0] += av.x * bv.x; acc[0][1] += av.x * bv.y;
            acc[0][2] += av.x * bv.z; acc[0][3] += av.x * bv.w;
            acc[1][0] += av.y * bv.x; acc[1][1] += av.y * bv.y;
            acc[1][2] += av.y * bv.z; acc[1][3] += av.y * bv.w;
            acc[2][0] += av.z * bv.x; acc[2][1] += av.z * bv.y;
            acc[2][2] += av.z * bv.z; acc[2][3] += av.z * bv.w;
            acc[3][0] += av.w * bv.x; acc[3][1] += av.w * bv.y;
            acc[3][2] += av.w * bv.z; acc[3][3] += av.w * bv.w;
        }
    }
    float* dst = (q == 0 ? p0 : q == 1 ? p1 : q == 2 ? p2 : p3) + (size_t)b * 4096;
#pragma unroll
    for (int r = 0; r < 4; ++r)
#pragma unroll
        for (int c = 0; c < 4; ++c)
            dst[(i0 + r) * 64 + j0 + c] = acc[r][c];
}

// ---------------------------------------------------------------------------
// k_invpost: fused inversion + Newton refinement + P/M GEMMs. One block/batch.
// GJ phase (wave 0, no barriers): ping-pong sX <-> sR (distinct arrays kill
// the krow/rowp alias so all 32 ds_read_b128 cluster -> one LDS latency
// exposure per step; R8: 96 -> ~45 us). Then 4 waves: Newton + P/M GEMMs.
// ---------------------------------------------------------------------------
#define GJSTEP(RB, WB, KK)                                                    \
    {                                                                         \
        const float* krow = (RB) + (KK) * 68;                                 \
        const float* rowp = (RB) + lane * 68;                                 \
        float4 prow[16], own[16];                                             \
        _Pragma("unroll")                                                     \
        for (int bj = 0; bj < 16; ++bj) prow[bj] = *(const float4*)(krow + 4 * bj); \
        _Pragma("unroll")                                                     \
        for (int bj = 0; bj < 16; ++bj) own[bj] = *(const float4*)(rowp + 4 * bj);  \
        float p = krow[KK];                                                   \
        float c = rowp[KK];                                                   \
        float ps = (__builtin_fabsf(p) < 1e-12f) ? (p >= 0.f ? 1e-12f : -1e-12f) : p; \
        float pinv = __builtin_amdgcn_rcpf(ps);                               \
        bool isk = (lane == (KK));                                            \
        float n  = isk ? 0.0f : 1.0f;                                         \
        float m2 = isk ? -pinv : c * pinv;                                    \
        float* wr = (WB) + lane * 68;                                         \
        _Pragma("unroll")                                                     \
        for (int bj = 0; bj < 16; ++bj) {                                     \
            float4 res;                                                       \
            res.x = own[bj].x * n - m2 * prow[bj].x;                          \
            res.y = own[bj].y * n - m2 * prow[bj].y;                          \
            res.z = own[bj].z * n - m2 * prow[bj].z;                          \
            res.w = own[bj].w * n - m2 * prow[bj].w;                          \
            *(float4*)(wr + 4 * bj) = res;                                    \
        }                                                                     \
        wr[KK] = isk ? pinv : -m2;   /* column-k fix, lands after row write */\
    }

#define GEMMT(Ash, Bsh)                                                       \
    {                                                                         \
        _Pragma("unroll")                                                     \
        for (int rr = 0; rr < 4; ++rr)                                        \
            for (int cc = 0; cc < 4; ++cc) acc[rr][cc] = 0.f;                 \
        _Pragma("unroll 4")                                                   \
        for (int kk = 0; kk < 64; kk += 4) {                                  \
            float4 av[4], bv[4];                                              \
            _Pragma("unroll")                                                 \
            for (int qq = 0; qq < 4; ++qq) {                                  \
                av[qq] = *(const float4*)((Ash) + (kk + qq) * 68 + i0);       \
                bv[qq] = *(const float4*)((Bsh) + (kk + qq) * 68 + j0);       \
            }                                                                 \
            _Pragma("unroll")                                                 \
            for (int qq = 0; qq < 4; ++qq) {                                  \
                acc[0][0] += av[qq].x * bv[qq].x; acc[0][1] += av[qq].x * bv[qq].y; \
                acc[0][2] += av[qq].x * bv[qq].z; acc[0][3] += av[qq].x * bv[qq].w; \
                acc[1][0] += av[qq].y * bv[qq].x; acc[1][1] += av[qq].y * bv[qq].y; \
                acc[1][2] += av[qq].y * bv[qq].z; acc[1][3] += av[qq].y * bv[qq].w; \
                acc[2][0] += av[qq].z * bv[qq].x; acc[2][1] += av[qq].z * bv[qq].y; \
                acc[2][2] += av[qq].z * bv[qq].z; acc[2][3] += av[qq].z * bv[qq].w; \
                acc[3][0] += av[qq].w * bv[qq].x; acc[3][1] += av[qq].w * bv[qq].y; \
                acc[3][2] += av[qq].w * bv[qq].z; acc[3][3] += av[qq].w * bv[qq].w; \
            }                                                                 \
        }                                                                     \
    }

__global__ __launch_bounds__(256, 1) void k_invpost(const float* p0, const float* p1,
                                                    const float* p2, const float* p3,
                                                    const float* Dws,
                                                    float* Sbuf, float* Mbuf) {
    __shared__ float sX[64 * 68];   // GJ ping-pong even / final X / later D
    __shared__ float sA[64 * 68];   // Sigma copy -> X2
    __shared__ float sR[64 * 68];   // GJ ping-pong odd / R -> P
    int t = threadIdx.x, b = blockIdx.x;
    size_t boff = (size_t)b * 4096;

    // D into registers (latency hidden behind GJ phase)
    float4 dreg[4];
#pragma unroll
    for (int u = 0; u < 4; ++u)
        dreg[u] = ((const float4*)(Dws + boff))[u * 256 + t];

    // stage Sigma = p0+p1+p2+p3 + 0.1 I into sX and sA
#pragma unroll
    for (int u = 0; u < 4; ++u) {
        int idx = u * 1024 + t * 4;
        int i = idx >> 6, j = idx & 63;
        float4 v0 = *(const float4*)(p0 + boff + idx);
        float4 v1 = *(const float4*)(p1 + boff + idx);
        float4 v2 = *(const float4*)(p2 + boff + idx);
        float4 v3 = *(const float4*)(p3 + boff + idx);
        float4 v = make_float4((v0.x + v1.x) + (v2.x + v3.x),
                               (v0.y + v1.y) + (v2.y + v3.y),
                               (v0.z + v1.z) + (v2.z + v3.z),
                               (v0.w + v1.w) + (v2.w + v3.w));
        int d = i - j;
        if (d >= 0 && d < 4) (&v.x)[d] += 0.1f;
        *(float4*)(sX + i * 68 + j) = v;
        *(float4*)(sA + i * 68 + j) = v;
    }
    __syncthreads();

    // ---- Gauss-Jordan, wave 0 only, ping-pong, no barriers ----
    if (t < 64) {
        int lane = t;
#pragma unroll 1
        for (int k2 = 0; k2 < 32; ++k2) {
            GJSTEP(sX, sR, 2 * k2);        // even step: sX -> sR
            GJSTEP(sR, sX, 2 * k2 + 1);    // odd step:  sR -> sX
        }
    }
    __syncthreads();

    int i0 = (t & 15) * 4, j0 = (t >> 4) * 4;
    float acc[4][4];

    // GEMM1: R = 2I - Sigma*X   (A = sA = Sigma, symmetric -> transposed read)
    GEMMT(sA, sX);
#pragma unroll
    for (int rr = 0; rr < 4; ++rr)
#pragma unroll
        for (int cc = 0; cc < 4; ++cc)
            sR[(i0 + rr) * 68 + j0 + cc] =
                ((i0 + rr) == (j0 + cc) ? 2.0f : 0.0f) - acc[rr][cc];
    __syncthreads();

    // GEMM2: X2 = X*R  (X symmetric)  -> Sbuf global + sA (Sigma dead)
    GEMMT(sX, sR);
#pragma unroll
    for (int rr = 0; rr < 4; ++rr) {
#pragma unroll
        for (int cc = 0; cc < 4; ++cc)
            sA[(i0 + rr) * 68 + j0 + cc] = acc[rr][cc];
        *(float4*)(Sbuf + boff + (i0 + rr) * 64 + j0) =
            make_float4(acc[rr][0], acc[rr][1], acc[rr][2], acc[rr][3]);
    }
    __syncthreads();

    // scatter D into sX (X dead)
#pragma unroll
    for (int u = 0; u < 4; ++u) {
        int idx = u * 1024 + t * 4;
        *(float4*)(sX + (idx >> 6) * 68 + (idx & 63)) = dreg[u];
    }
    __syncthreads();

    // GEMM3: P = D*X2  (D symmetric) -> sR (R dead)
    GEMMT(sX, sA);
    __syncthreads();
#pragma unroll
    for (int rr = 0; rr < 4; ++rr)
#pragma unroll
        for (int cc = 0; cc < 4; ++cc)
            sR[(i0 + rr) * 68 + j0 + cc] = acc[rr][cc];
    __syncthreads();

    // GEMM4: M = X2*P  (X2 symmetric) -> Mbuf
    GEMMT(sA, sR);
#pragma unroll
    for (int rr = 0; rr < 4; ++rr)
        *(float4*)(Mbuf + boff + (i0 + rr) * 64 + j0) =
            make_float4(acc[rr][0], acc[rr][1], acc[rr][2], acc[rr][3]);
}

// ---------------------------------------------------------------------------
// k_feat v6: register-tiled dual-GEMM, all operands in LDS. R12 counters:
// VALU 55% (~31us = FMA floor) AND LDS pipe ~55% (~31us) -> both half-idle,
// poorly overlapped at 2 blocks/CU (64KB LDS, 2 waves/SIMD). Fix: A staged
// in EIGHT 8-k phases, double-buffered (2x8KB) -> LDS 48KB -> 3 blocks/CU
// (3 waves/SIMD TLP); one barrier per phase; staging global loads issued
// before the 1024-FMA phase body so vmcnt hides under compute.
// ---------------------------------------------------------------------------
__global__ __launch_bounds__(256, 1) void k_feat(const float* __restrict__ A,
                                                 const float* __restrict__ Sbuf,
                                                 const float* __restrict__ Mbuf,
                                                 float* __restrict__ T1,
                                                 float* __restrict__ T2) {
    __shared__ float sS[4096];
    __shared__ float sM[4096];
    __shared__ float sa[2][2048];   // A-tile double buffer: [8 k][256 g] each
    int t = threadIdx.x;
    int b = blockIdx.x >> 3, tile = blockIdx.x & 7;
    const float* Abase = A + tile * 256;
    {
        const float4* S4 = (const float4*)(Sbuf + (size_t)b * 4096);
        const float4* M4 = (const float4*)(Mbuf + (size_t)b * 4096);
#pragma unroll
        for (int u = 0; u < 4; ++u) {
            ((float4*)sS)[u * 256 + t] = S4[u * 256 + t];
            ((float4*)sM)[u * 256 + t] = M4[u * 256 + t];
        }
        // stage A phase 0 (k = 0..7)
#pragma unroll
        for (int u = 0; u < 2; ++u) {
            int idx = u * 1024 + t * 4;
            int kk = idx >> 8, gl = idx & 255;
            *(float4*)(&sa[0][0] + idx) = *(const float4*)(Abase + (size_t)kk * NG + gl);
        }
    }
    int iq = t >> 4, gq = t & 15;
    int i0 = iq * 4;
    float accS[4][16], accM[4][16];
#pragma unroll
    for (int r = 0; r < 4; ++r)
#pragma unroll
        for (int c = 0; c < 16; ++c) { accS[r][c] = 0.f; accM[r][c] = 0.f; }
    __syncthreads();

#pragma unroll 1
    for (int p = 0; p < 8; ++p) {
        const float* buf = &sa[p & 1][0];
        // issue next phase's global loads first (hidden under this phase's FMAs)
        float4 st0, st1;
        int i0s = 0, i1s = 0;
        if (p < 7) {
            int kb = (p + 1) * 8;
            i0s = t * 4;              // u = 0
            i1s = 1024 + t * 4;       // u = 1
            st0 = *(const float4*)(Abase + (size_t)(kb + (i0s >> 8)) * NG + (i0s & 255));
            st1 = *(const float4*)(Abase + (size_t)(kb + (i1s >> 8)) * NG + (i1s & 255));
        }
#pragma unroll
        for (int kk = 0; kk < 8; ++kk) {
            int k = p * 8 + kk;
            float4 sf = *(const float4*)(sS + k * 64 + i0);   // S[i0..3][k]
            float4 mf = *(const float4*)(sM + k * 64 + i0);   // M[i0..3][k]
            const float* ak = buf + kk * 256 + gq * 4;
            float4 a0 = *(const float4*)(ak);
            float4 a1 = *(const float4*)(ak + 64);
            float4 a2 = *(const float4*)(ak + 128);
            float4 a3 = *(const float4*)(ak + 192);
            float af[16] = {a0.x, a0.y, a0.z, a0.w, a1.x, a1.y, a1.z, a1.w,
                            a2.x, a2.y, a2.z, a2.w, a3.x, a3.y, a3.z, a3.w};
#pragma unroll
            for (int r = 0; r < 4; ++r) {
                float sr = (&sf.x)[r];
                float mr = (&mf.x)[r];
#pragma unroll
                for (int c = 0; c < 16; ++c) {
                    accS[r][c] += sr * af[c];
                    accM[r][c] += mr * af[c];
                }
            }
        }
        if (p < 7) {
            float* nb = &sa[(p + 1) & 1][0];
            *(float4*)(nb + i0s) = st0;
            *(float4*)(nb + i1s) = st1;
        }
        __syncthreads();
    }

    // epilogue: multiply by own A rows (global, one-shot, L1-hot)
    float pS[16], pM[16];
#pragma unroll
    for (int c = 0; c < 16; ++c) { pS[c] = 0.f; pM[c] = 0.f; }
#pragma unroll
    for (int r = 0; r < 4; ++r) {
        const float* arp = A + (size_t)(i0 + r) * NG + tile * 256 + gq * 4;
        float4 b0 = *(const float4*)(arp);
        float4 b1 = *(const float4*)(arp + 64);
        float4 b2 = *(const float4*)(arp + 128);
        float4 b3 = *(const float4*)(arp + 192);
        float ar[16] = {b0.x, b0.y, b0.z, b0.w, b1.x, b1.y, b1.z, b1.w,
                        b2.x, b2.y, b2.z, b2.w, b3.x, b3.y, b3.z, b3.w};
#pragma unroll
        for (int c = 0; c < 16; ++c) {
            pS[c] += ar[c] * accS[r][c];
            pM[c] += ar[c] * accM[r][c];
        }
    }
    __syncthreads();   // k-loop reads of sS/sM done; reuse as scratch

    // scratch: sS[iq][g_local] S-partials, sM likewise (16 x 256)
#pragma unroll
    for (int ch = 0; ch < 4; ++ch) {
        *(float4*)(sS + iq * 256 + ch * 64 + gq * 4) =
            make_float4(pS[ch * 4], pS[ch * 4 + 1], pS[ch * 4 + 2], pS[ch * 4 + 3]);
        *(float4*)(sM + iq * 256 + ch * 64 + gq * 4) =
            make_float4(pM[ch * 4], pM[ch * 4 + 1], pM[ch * 4 + 2], pM[ch * 4 + 3]);
    }
    __syncthreads();

    // final 16-way reduce: thread t owns g_local = t (lanes consecutive: no conflict)
    float sumS = 0.f, sumM = 0.f;
#pragma unroll
    for (int q = 0; q < 16; ++q) {
        sumS += sS[q * 256 + t];
        sumM += sM[q * 256 + t];
    }
    size_t base = (size_t)b * NG + tile * 256 + t;
    T2[base] = fabsf(sumS);
    T1[base] = sumM;
}

// ---------------------------------------------------------------------------
// k_mlp v2: per-gridpoint MLP, 4 batch-points processed JOINTLY per thread so
// every W1/W2/W3 LDS read is amortized 4x. v1 audit: ~1150 ds_read_b128 per
// thread (W2 re-read per batch-point) = ~23us LDS-pipe floor vs ~4us VALU —
// grossly LDS-bound. v2: ~290 b128/thread -> ~6us LDS, FMA count unchanged,
// numerics identical per batch-point. h1[4][32] lives in registers
// (~200 VGPR, launch_bounds(256,1); grid=256 -> 1 block/CU regardless).
// ---------------------------------------------------------------------------
__global__ __launch_bounds__(256, 1) void k_mlp(const float* __restrict__ T1,
                                                const float* __restrict__ T2,
                                                const float* __restrict__ gcur,
                                                const float* __restrict__ W1,
                                                const float* __restrict__ b1,
                                                const float* __restrict__ W2,
                                                const float* __restrict__ b2,
                                                const float* __restrict__ W3,
                                                const float* __restrict__ b3,
                                                int it, float* __restrict__ out) {
    __shared__ float w[8 * 1220];
    int t = threadIdx.x, g0 = blockIdx.x * 8;
    for (int gl = 0; gl < 8; ++gl) {
        size_t gi = (size_t)it * NG + g0 + gl;
        float* wd = &w[gl * 1220];
        if (t < 96) wd[t] = W1[gi * 96 + t];
        else if (t < 128) wd[t] = b1[gi * 32 + (t - 96)];
        const float* w2 = W2 + gi * 1024;
#pragma unroll
        for (int u = 0; u < 4; ++u) wd[128 + u * 256 + t] = w2[u * 256 + t];
        if (t < 32) wd[1152 + t] = b2[gi * 32 + t];
        else if (t < 64) wd[1184 + (t - 32)] = W3[gi * 32 + (t - 32)];
        else if (t == 64) wd[1216] = b3[gi];
    }
    __syncthreads();
    int gl = t & 7, gg = g0 + gl;
    const float* wd = &w[gl * 1220];
    int b0 = t >> 3;                 // 0..31; batch points b0 + {0,32,64,96}

    // load the 4 batch-points' inputs
    float x0[4], x1[4], x2[4];
#pragma unroll
    for (int c = 0; c < 4; ++c) {
        size_t xo = (size_t)(b0 + c * 32) * NG + gg;
        x0[c] = T1[xo]; x1[c] = T2[xo]; x2[c] = gcur[xo];
    }

    // layer 1 (weights read once for all 4 b's)
    float h1[4][32];
#pragma unroll
    for (int k = 0; k < 32; k += 4) {
        float4 wa = *(const float4*)(wd + k);
        float4 wb = *(const float4*)(wd + 32 + k);
        float4 wc = *(const float4*)(wd + 64 + k);
        float4 bv = *(const float4*)(wd + 96 + k);
#pragma unroll
        for (int c = 0; c < 4; ++c) {
            h1[c][k + 0] = fmaxf(0.f, x0[c] * wa.x + x1[c] * wb.x + x2[c] * wc.x + bv.x);
            h1[c][k + 1] = fmaxf(0.f, x0[c] * wa.y + x1[c] * wb.y + x2[c] * wc.y + bv.y);
            h1[c][k + 2] = fmaxf(0.f, x0[c] * wa.z + x1[c] * wb.z + x2[c] * wc.z + bv.z);
            h1[c][k + 3] = fmaxf(0.f, x0[c] * wa.w + x1[c] * wb.w + x2[c] * wc.w + bv.w);
        }
    }

    // layers 2+3 (W2 column-group read once for all 4 b's)
    float acc[4];
    float b3v = wd[1216];
#pragma unroll
    for (int c = 0; c < 4; ++c) acc[c] = b3v;
#pragma unroll 1
    for (int k = 0; k < 32; k += 4) {
        float4 hb = *(const float4*)(wd + 1152 + k);
        float v[4][4];
#pragma unroll
        for (int c = 0; c < 4; ++c) {
            v[c][0] = hb.x; v[c][1] = hb.y; v[c][2] = hb.z; v[c][3] = hb.w;
        }
#pragma unroll
        for (int j = 0; j < 32; ++j) {
            float4 w2v = *(const float4*)(wd + 128 + j * 32 + k);
#pragma unroll
            for (int c = 0; c < 4; ++c) {
                v[c][0] += h1[c][j] * w2v.x;
                v[c][1] += h1[c][j] * w2v.y;
                v[c][2] += h1[c][j] * w2v.z;
                v[c][3] += h1[c][j] * w2v.w;
            }
        }
        float4 w3v = *(const float4*)(wd + 1184 + k);
#pragma unroll
        for (int c = 0; c < 4; ++c) {
            acc[c] += fmaxf(0.f, v[c][0]) * w3v.x + fmaxf(0.f, v[c][1]) * w3v.y +
                      fmaxf(0.f, v[c][2]) * w3v.z + fmaxf(0.f, v[c][3]) * w3v.w;
        }
    }
#pragma unroll
    for (int c = 0; c < 4; ++c)
        out[(size_t)(b0 + c * 32) * NG + gg] = acc[c];
}

extern "C" void kernel_launch(void* const* d_in, const int* in_sizes, int n_in,
                              void* d_out, int out_size, void* d_ws, size_t ws_size,
                              hipStream_t stream) {
    const float* data = (const float*)d_in[0];
    const float* A    = (const float*)d_in[1];
    const float* W1   = (const float*)d_in[2];
    const float* b1   = (const float*)d_in[3];
    const float* W2   = (const float*)d_in[4];
    const float* b2   = (const float*)d_in[5];
    const float* W3   = (const float*)d_in[6];
    const float* b3   = (const float*)d_in[7];
    float* out = (float*)d_out;
    float* ws = (float*)d_ws;

    float* D  = ws;
    float* P0 = ws + 524288;    // becomes S
    float* P1 = ws + 1048576;   // becomes M
    float* P2 = ws + 1572864;
    float* P3 = ws + 2097152;
    float* T1 = ws + 2621440;
    float* T2 = ws + 2883584;
    float* gA = ws + 3145728;
    float* gB = ws + 3407872;

    k_init<<<dim3(1024), dim3(256), 0, stream>>>(gA);
    k_D<<<dim3(128), dim3(256), 0, stream>>>(data, D);

    float* gc = gA;
    float* gn = gB;
    for (int it = 0; it < 3; ++it) {
        k_cov<<<dim3(512), dim3(256), 0, stream>>>(A, gc, P0, P1, P2, P3);
        k_invpost<<<dim3(128), dim3(256), 0, stream>>>(P0, P1, P2, P3, D, P0, P1);
        k_feat<<<dim3(1024), dim3(256), 0, stream>>>(A, P0, P1, T1, T2);
        float* dst = (it == 2) ? out : gn;
        k_mlp<<<dim3(256), dim3(256), 0, stream>>>(T1, T2, gc, W1, b1, W2, b2, W3, b3, it, dst);
        float* tmp = gc; gc = gn; gn = tmp;
    }
}

// Round 14
// 586.633 us; speedup vs baseline: 1.0691x; 1.0691x over previous
//
#include <hip/hip_runtime.h>

// Problem constants
#define NB 128      // batch
#define NM 64       // sensors
#define NT 128      // snapshots
#define NG 2048     // gridpoints
#define NH 32       // hidden
// VAR_NOISE = 0.1f

// ---------------------------------------------------------------------------
// Workspace layout (floats):
//  D   [128*64*64]   off 0
//  P0  [128*64*64]   off 524288   (cov partial q0; k_invpost overwrites with S)
//  P1  [128*64*64]   off 1048576  (cov partial q1; k_invpost overwrites with M)
//  P2  [128*64*64]   off 1572864  (cov partial q2)
//  P3  [128*64*64]   off 2097152  (cov partial q3)
//  T1  [128*2048]    off 2621440
//  T2  [128*2048]    off 2883584
//  gA  [128*2048]    off 3145728
//  gB  [128*2048]    off 3407872
// ---------------------------------------------------------------------------

__global__ __launch_bounds__(256) void k_init(float* __restrict__ g) {
    g[blockIdx.x * 256 + threadIdx.x] = 1.0f;
}

// D[b] = data[b] * data[b]^T / NT    (once per call; data constant)
__global__ __launch_bounds__(256) void k_D(const float* __restrict__ data,
                                           float* __restrict__ D) {
    __shared__ float sd[64 * 133];
    int b = blockIdx.x, t = threadIdx.x;
    const float* db = data + (size_t)b * 8192;
    for (int idx = t; idx < 8192; idx += 256)
        sd[(idx >> 7) * 133 + (idx & 127)] = db[idx];
    __syncthreads();
    int i0 = (t & 15) * 4, j0 = (t >> 4) * 4;
    float acc[4][4];
#pragma unroll
    for (int r = 0; r < 4; ++r)
#pragma unroll
        for (int c = 0; c < 4; ++c) acc[r][c] = 0.f;
    for (int tt = 0; tt < 128; ++tt) {
        float av[4], bv[4];
#pragma unroll
        for (int r = 0; r < 4; ++r) av[r] = sd[(i0 + r) * 133 + tt];
#pragma unroll
        for (int c = 0; c < 4; ++c) bv[c] = sd[(j0 + c) * 133 + tt];
#pragma unroll
        for (int r = 0; r < 4; ++r)
#pragma unroll
            for (int c = 0; c < 4; ++c) acc[r][c] += av[r] * bv[c];
    }
    float* Db = D + (size_t)b * 4096;
#pragma unroll
    for (int r = 0; r < 4; ++r)
#pragma unroll
        for (int c = 0; c < 4; ++c)
            Db[(i0 + r) * 64 + j0 + c] = acc[r][c] * (1.0f / 128.0f);
}

// Partial covariance: block (b, quarter q) accumulates over 512 g's.
__global__ __launch_bounds__(256) void k_cov(const float* __restrict__ A,
                                             const float* __restrict__ g,
                                             float* __restrict__ p0,
                                             float* __restrict__ p1,
                                             float* __restrict__ p2,
                                             float* __restrict__ p3) {
    int b = blockIdx.x >> 2, q = blockIdx.x & 3, t = threadIdx.x;
    int goff = q * 512;
    __shared__ float sA[32 * 64];    // [gg][m]
    __shared__ float sAg[32 * 64];   // scaled by gamma
    __shared__ float sg[512];
    for (int idx = t; idx < 512; idx += 256)
        sg[idx] = g[(size_t)b * NG + goff + idx];
    float acc[4][4];
#pragma unroll
    for (int r = 0; r < 4; ++r)
#pragma unroll
        for (int c = 0; c < 4; ++c) acc[r][c] = 0.f;
    int i0 = (t & 15) * 4, j0 = (t >> 4) * 4;
    int m = t >> 2, gs = (t & 3) * 8;
    __syncthreads();
    for (int ch = 0; ch < 16; ++ch) {
        const float* Ar = A + (size_t)m * NG + goff + ch * 32 + gs;
        float4 v0 = *(const float4*)Ar;
        float4 v1 = *(const float4*)(Ar + 4);
        __syncthreads();
        sA[(gs + 0) * 64 + m] = v0.x; sAg[(gs + 0) * 64 + m] = v0.x * sg[ch * 32 + gs + 0];
        sA[(gs + 1) * 64 + m] = v0.y; sAg[(gs + 1) * 64 + m] = v0.y * sg[ch * 32 + gs + 1];
        sA[(gs + 2) * 64 + m] = v0.z; sAg[(gs + 2) * 64 + m] = v0.z * sg[ch * 32 + gs + 2];
        sA[(gs + 3) * 64 + m] = v0.w; sAg[(gs + 3) * 64 + m] = v0.w * sg[ch * 32 + gs + 3];
        sA[(gs + 4) * 64 + m] = v1.x; sAg[(gs + 4) * 64 + m] = v1.x * sg[ch * 32 + gs + 4];
        sA[(gs + 5) * 64 + m] = v1.y; sAg[(gs + 5) * 64 + m] = v1.y * sg[ch * 32 + gs + 5];
        sA[(gs + 6) * 64 + m] = v1.z; sAg[(gs + 6) * 64 + m] = v1.z * sg[ch * 32 + gs + 6];
        sA[(gs + 7) * 64 + m] = v1.w; sAg[(gs + 7) * 64 + m] = v1.w * sg[ch * 32 + gs + 7];
        __syncthreads();
#pragma unroll
        for (int gg = 0; gg < 32; ++gg) {
            float4 av = *(const float4*)&sAg[gg * 64 + i0];
            float4 bv = *(const float4*)&sA[gg * 64 + j0];
            acc[0][0] += av.x * bv.x; acc[0][1] += av.x * bv.y;
            acc[0][2] += av.x * bv.z; acc[0][3] += av.x * bv.w;
            acc[1][0] += av.y * bv.x; acc[1][1] += av.y * bv.y;
            acc[1][2] += av.y * bv.z; acc[1][3] += av.y * bv.w;
            acc[2][0] += av.z * bv.x; acc[2][1] += av.z * bv.y;
            acc[2][2] += av.z * bv.z; acc[2][3] += av.z * bv.w;
            acc[3][0] += av.w * bv.x; acc[3][1] += av.w * bv.y;
            acc[3][2] += av.w * bv.z; acc[3][3] += av.w * bv.w;
        }
    }
    float* dst = (q == 0 ? p0 : q == 1 ? p1 : q == 2 ? p2 : p3) + (size_t)b * 4096;
#pragma unroll
    for (int r = 0; r < 4; ++r)
#pragma unroll
        for (int c = 0; c < 4; ++c)
            dst[(i0 + r) * 64 + j0 + c] = acc[r][c];
}

// ---------------------------------------------------------------------------
// k_invpost: fused inversion + Newton refinement + P/M GEMMs. One block/batch.
// GJ phase (wave 0, no barriers): ping-pong sX <-> sR (distinct arrays kill
// the krow/rowp alias so all 32 ds_read_b128 cluster -> one LDS latency
// exposure per step; R8: 96 -> ~45 us). Then 4 waves: Newton + P/M GEMMs.
// ---------------------------------------------------------------------------
#define GJSTEP(RB, WB, KK)                                                    \
    {                                                                         \
        const float* krow = (RB) + (KK) * 68;                                 \
        const float* rowp = (RB) + lane * 68;                                 \
        float4 prow[16], own[16];                                             \
        _Pragma("unroll")                                                     \
        for (int bj = 0; bj < 16; ++bj) prow[bj] = *(const float4*)(krow + 4 * bj); \
        _Pragma("unroll")                                                     \
        for (int bj = 0; bj < 16; ++bj) own[bj] = *(const float4*)(rowp + 4 * bj);  \
        float p = krow[KK];                                                   \
        float c = rowp[KK];                                                   \
        float ps = (__builtin_fabsf(p) < 1e-12f) ? (p >= 0.f ? 1e-12f : -1e-12f) : p; \
        float pinv = __builtin_amdgcn_rcpf(ps);                               \
        bool isk = (lane == (KK));                                            \
        float n  = isk ? 0.0f : 1.0f;                                         \
        float m2 = isk ? -pinv : c * pinv;                                    \
        float* wr = (WB) + lane * 68;                                         \
        _Pragma("unroll")                                                     \
        for (int bj = 0; bj < 16; ++bj) {                                     \
            float4 res;                                                       \
            res.x = own[bj].x * n - m2 * prow[bj].x;                          \
            res.y = own[bj].y * n - m2 * prow[bj].y;                          \
            res.z = own[bj].z * n - m2 * prow[bj].z;                          \
            res.w = own[bj].w * n - m2 * prow[bj].w;                          \
            *(float4*)(wr + 4 * bj) = res;                                    \
        }                                                                     \
        wr[KK] = isk ? pinv : -m2;   /* column-k fix, lands after row write */\
    }

#define GEMMT(Ash, Bsh)                                                       \
    {                                                                         \
        _Pragma("unroll")                                                     \
        for (int rr = 0; rr < 4; ++rr)                                        \
            for (int cc = 0; cc < 4; ++cc) acc[rr][cc] = 0.f;                 \
        _Pragma("unroll 4")                                                   \
        for (int kk = 0; kk < 64; kk += 4) {                                  \
            float4 av[4], bv[4];                                              \
            _Pragma("unroll")                                                 \
            for (int qq = 0; qq < 4; ++qq) {                                  \
                av[qq] = *(const float4*)((Ash) + (kk + qq) * 68 + i0);       \
                bv[qq] = *(const float4*)((Bsh) + (kk + qq) * 68 + j0);       \
            }                                                                 \
            _Pragma("unroll")                                                 \
            for (int qq = 0; qq < 4; ++qq) {                                  \
                acc[0][0] += av[qq].x * bv[qq].x; acc[0][1] += av[qq].x * bv[qq].y; \
                acc[0][2] += av[qq].x * bv[qq].z; acc[0][3] += av[qq].x * bv[qq].w; \
                acc[1][0] += av[qq].y * bv[qq].x; acc[1][1] += av[qq].y * bv[qq].y; \
                acc[1][2] += av[qq].y * bv[qq].z; acc[1][3] += av[qq].y * bv[qq].w; \
                acc[2][0] += av[qq].z * bv[qq].x; acc[2][1] += av[qq].z * bv[qq].y; \
                acc[2][2] += av[qq].z * bv[qq].z; acc[2][3] += av[qq].z * bv[qq].w; \
                acc[3][0] += av[qq].w * bv[qq].x; acc[3][1] += av[qq].w * bv[qq].y; \
                acc[3][2] += av[qq].w * bv[qq].z; acc[3][3] += av[qq].w * bv[qq].w; \
            }                                                                 \
        }                                                                     \
    }

__global__ __launch_bounds__(256, 1) void k_invpost(const float* p0, const float* p1,
                                                    const float* p2, const float* p3,
                                                    const float* Dws,
                                                    float* Sbuf, float* Mbuf) {
    __shared__ float sX[64 * 68];   // GJ ping-pong even / final X / later D
    __shared__ float sA[64 * 68];   // Sigma copy -> X2
    __shared__ float sR[64 * 68];   // GJ ping-pong odd / R -> P
    int t = threadIdx.x, b = blockIdx.x;
    size_t boff = (size_t)b * 4096;

    // D into registers (latency hidden behind GJ phase)
    float4 dreg[4];
#pragma unroll
    for (int u = 0; u < 4; ++u)
        dreg[u] = ((const float4*)(Dws + boff))[u * 256 + t];

    // stage Sigma = p0+p1+p2+p3 + 0.1 I into sX and sA
#pragma unroll
    for (int u = 0; u < 4; ++u) {
        int idx = u * 1024 + t * 4;
        int i = idx >> 6, j = idx & 63;
        float4 v0 = *(const float4*)(p0 + boff + idx);
        float4 v1 = *(const float4*)(p1 + boff + idx);
        float4 v2 = *(const float4*)(p2 + boff + idx);
        float4 v3 = *(const float4*)(p3 + boff + idx);
        float4 v = make_float4((v0.x + v1.x) + (v2.x + v3.x),
                               (v0.y + v1.y) + (v2.y + v3.y),
                               (v0.z + v1.z) + (v2.z + v3.z),
                               (v0.w + v1.w) + (v2.w + v3.w));
        int d = i - j;
        if (d >= 0 && d < 4) (&v.x)[d] += 0.1f;
        *(float4*)(sX + i * 68 + j) = v;
        *(float4*)(sA + i * 68 + j) = v;
    }
    __syncthreads();

    // ---- Gauss-Jordan, wave 0 only, ping-pong, no barriers ----
    if (t < 64) {
        int lane = t;
#pragma unroll 1
        for (int k2 = 0; k2 < 32; ++k2) {
            GJSTEP(sX, sR, 2 * k2);        // even step: sX -> sR
            GJSTEP(sR, sX, 2 * k2 + 1);    // odd step:  sR -> sX
        }
    }
    __syncthreads();

    int i0 = (t & 15) * 4, j0 = (t >> 4) * 4;
    float acc[4][4];

    // GEMM1: R = 2I - Sigma*X   (A = sA = Sigma, symmetric -> transposed read)
    GEMMT(sA, sX);
#pragma unroll
    for (int rr = 0; rr < 4; ++rr)
#pragma unroll
        for (int cc = 0; cc < 4; ++cc)
            sR[(i0 + rr) * 68 + j0 + cc] =
                ((i0 + rr) == (j0 + cc) ? 2.0f : 0.0f) - acc[rr][cc];
    __syncthreads();

    // GEMM2: X2 = X*R  (X symmetric)  -> Sbuf global + sA (Sigma dead)
    GEMMT(sX, sR);
#pragma unroll
    for (int rr = 0; rr < 4; ++rr) {
#pragma unroll
        for (int cc = 0; cc < 4; ++cc)
            sA[(i0 + rr) * 68 + j0 + cc] = acc[rr][cc];
        *(float4*)(Sbuf + boff + (i0 + rr) * 64 + j0) =
            make_float4(acc[rr][0], acc[rr][1], acc[rr][2], acc[rr][3]);
    }
    __syncthreads();

    // scatter D into sX (X dead)
#pragma unroll
    for (int u = 0; u < 4; ++u) {
        int idx = u * 1024 + t * 4;
        *(float4*)(sX + (idx >> 6) * 68 + (idx & 63)) = dreg[u];
    }
    __syncthreads();

    // GEMM3: P = D*X2  (D symmetric) -> sR (R dead)
    GEMMT(sX, sA);
    __syncthreads();
#pragma unroll
    for (int rr = 0; rr < 4; ++rr)
#pragma unroll
        for (int cc = 0; cc < 4; ++cc)
            sR[(i0 + rr) * 68 + j0 + cc] = acc[rr][cc];
    __syncthreads();

    // GEMM4: M = X2*P  (X2 symmetric) -> Mbuf
    GEMMT(sA, sR);
#pragma unroll
    for (int rr = 0; rr < 4; ++rr)
        *(float4*)(Mbuf + boff + (i0 + rr) * 64 + j0) =
            make_float4(acc[rr][0], acc[rr][1], acc[rr][2], acc[rr][3]);
}

// ---------------------------------------------------------------------------
// k_feat v7: v5's proven inner loop (108 VGPR) + SINGLE-buffered 16-k A
// phases. R13 post-mortem: double-buffer + register prefetch bloated VGPR to
// 176 -> 2 waves/SIMD cap -> 48KB LDS never bought the 3rd block/CU and 8
// barriers added stall (77.7us). Constraints for 3 blocks/CU: LDS<=53KB AND
// VGPR<=170. v7: sa[16][256] = 16KB -> LDS 48KB, no prefetch regs -> VGPR
// ~110. 4 phases x 2 barriers; at 12 waves/CU cross-block TLP covers barrier
// drains + staging latency, letting the two ~31us pipe budgets (VALU, LDS)
// overlap toward max ~33us.
// ---------------------------------------------------------------------------
__global__ __launch_bounds__(256, 1) void k_feat(const float* __restrict__ A,
                                                 const float* __restrict__ Sbuf,
                                                 const float* __restrict__ Mbuf,
                                                 float* __restrict__ T1,
                                                 float* __restrict__ T2) {
    __shared__ float sS[4096];
    __shared__ float sM[4096];
    __shared__ float sa[4096];     // A-tile phase buffer: [16 k][256 g]
    int t = threadIdx.x;
    int b = blockIdx.x >> 3, tile = blockIdx.x & 7;
    const float* Abase = A + tile * 256;
    {
        const float4* S4 = (const float4*)(Sbuf + (size_t)b * 4096);
        const float4* M4 = (const float4*)(Mbuf + (size_t)b * 4096);
#pragma unroll
        for (int u = 0; u < 4; ++u) {
            ((float4*)sS)[u * 256 + t] = S4[u * 256 + t];
            ((float4*)sM)[u * 256 + t] = M4[u * 256 + t];
        }
        // stage A phase 0 (k = 0..15)
#pragma unroll
        for (int u = 0; u < 4; ++u) {
            int idx = u * 1024 + t * 4;
            int kk = idx >> 8, gl = idx & 255;
            *(float4*)(sa + idx) = *(const float4*)(Abase + (size_t)kk * NG + gl);
        }
    }
    int iq = t >> 4, gq = t & 15;
    int i0 = iq * 4;
    float accS[4][16], accM[4][16];
#pragma unroll
    for (int r = 0; r < 4; ++r)
#pragma unroll
        for (int c = 0; c < 16; ++c) { accS[r][c] = 0.f; accM[r][c] = 0.f; }
    __syncthreads();

#pragma unroll 1
    for (int p = 0; p < 4; ++p) {
        if (p) {
            __syncthreads();   // previous phase's sa reads complete
#pragma unroll
            for (int u = 0; u < 4; ++u) {
                int idx = u * 1024 + t * 4;
                int kk = idx >> 8, gl = idx & 255;
                *(float4*)(sa + idx) =
                    *(const float4*)(Abase + (size_t)(p * 16 + kk) * NG + gl);
            }
            __syncthreads();
        }
#pragma unroll 2
        for (int kk = 0; kk < 16; ++kk) {
            int k = p * 16 + kk;
            float4 sf = *(const float4*)(sS + k * 64 + i0);   // S[i0..3][k]
            float4 mf = *(const float4*)(sM + k * 64 + i0);   // M[i0..3][k]
            const float* ak = sa + kk * 256 + gq * 4;
            float4 a0 = *(const float4*)(ak);
            float4 a1 = *(const float4*)(ak + 64);
            float4 a2 = *(const float4*)(ak + 128);
            float4 a3 = *(const float4*)(ak + 192);
            float af[16] = {a0.x, a0.y, a0.z, a0.w, a1.x, a1.y, a1.z, a1.w,
                            a2.x, a2.y, a2.z, a2.w, a3.x, a3.y, a3.z, a3.w};
#pragma unroll
            for (int r = 0; r < 4; ++r) {
                float sr = (&sf.x)[r];
                float mr = (&mf.x)[r];
#pragma unroll
                for (int c = 0; c < 16; ++c) {
                    accS[r][c] += sr * af[c];
                    accM[r][c] += mr * af[c];
                }
            }
        }
    }

    // epilogue: multiply by own A rows (global, one-shot, L1-hot)
    float pS[16], pM[16];
#pragma unroll
    for (int c = 0; c < 16; ++c) { pS[c] = 0.f; pM[c] = 0.f; }
#pragma unroll
    for (int r = 0; r < 4; ++r) {
        const float* arp = A + (size_t)(i0 + r) * NG + tile * 256 + gq * 4;
        float4 b0 = *(const float4*)(arp);
        float4 b1 = *(const float4*)(arp + 64);
        float4 b2 = *(const float4*)(arp + 128);
        float4 b3 = *(const float4*)(arp + 192);
        float ar[16] = {b0.x, b0.y, b0.z, b0.w, b1.x, b1.y, b1.z, b1.w,
                        b2.x, b2.y, b2.z, b2.w, b3.x, b3.y, b3.z, b3.w};
#pragma unroll
        for (int c = 0; c < 16; ++c) {
            pS[c] += ar[c] * accS[r][c];
            pM[c] += ar[c] * accM[r][c];
        }
    }
    __syncthreads();   // k-loop reads of sS/sM done; reuse as scratch

    // scratch: sS[iq][g_local] S-partials, sM likewise (16 x 256)
#pragma unroll
    for (int ch = 0; ch < 4; ++ch) {
        *(float4*)(sS + iq * 256 + ch * 64 + gq * 4) =
            make_float4(pS[ch * 4], pS[ch * 4 + 1], pS[ch * 4 + 2], pS[ch * 4 + 3]);
        *(float4*)(sM + iq * 256 + ch * 64 + gq * 4) =
            make_float4(pM[ch * 4], pM[ch * 4 + 1], pM[ch * 4 + 2], pM[ch * 4 + 3]);
    }
    __syncthreads();

    // final 16-way reduce: thread t owns g_local = t (lanes consecutive: no conflict)
    float sumS = 0.f, sumM = 0.f;
#pragma unroll
    for (int q = 0; q < 16; ++q) {
        sumS += sS[q * 256 + t];
        sumM += sM[q * 256 + t];
    }
    size_t base = (size_t)b * NG + tile * 256 + t;
    T2[base] = fabsf(sumS);
    T1[base] = sumM;
}

// ---------------------------------------------------------------------------
// k_mlp v2 (kept from R13 — saved ~17us/iter): 4 batch-points jointly per
// thread so every W1/W2/W3 LDS read amortizes 4x (~1150 -> ~290 b128/thread).
// ---------------------------------------------------------------------------
__global__ __launch_bounds__(256, 1) void k_mlp(const float* __restrict__ T1,
                                                const float* __restrict__ T2,
                                                const float* __restrict__ gcur,
                                                const float* __restrict__ W1,
                                                const float* __restrict__ b1,
                                                const float* __restrict__ W2,
                                                const float* __restrict__ b2,
                                                const float* __restrict__ W3,
                                                const float* __restrict__ b3,
                                                int it, float* __restrict__ out) {
    __shared__ float w[8 * 1220];
    int t = threadIdx.x, g0 = blockIdx.x * 8;
    for (int gl = 0; gl < 8; ++gl) {
        size_t gi = (size_t)it * NG + g0 + gl;
        float* wd = &w[gl * 1220];
        if (t < 96) wd[t] = W1[gi * 96 + t];
        else if (t < 128) wd[t] = b1[gi * 32 + (t - 96)];
        const float* w2 = W2 + gi * 1024;
#pragma unroll
        for (int u = 0; u < 4; ++u) wd[128 + u * 256 + t] = w2[u * 256 + t];
        if (t < 32) wd[1152 + t] = b2[gi * 32 + t];
        else if (t < 64) wd[1184 + (t - 32)] = W3[gi * 32 + (t - 32)];
        else if (t == 64) wd[1216] = b3[gi];
    }
    __syncthreads();
    int gl = t & 7, gg = g0 + gl;
    const float* wd = &w[gl * 1220];
    int b0 = t >> 3;                 // 0..31; batch points b0 + {0,32,64,96}

    float x0[4], x1[4], x2[4];
#pragma unroll
    for (int c = 0; c < 4; ++c) {
        size_t xo = (size_t)(b0 + c * 32) * NG + gg;
        x0[c] = T1[xo]; x1[c] = T2[xo]; x2[c] = gcur[xo];
    }

    float h1[4][32];
#pragma unroll
    for (int k = 0; k < 32; k += 4) {
        float4 wa = *(const float4*)(wd + k);
        float4 wb = *(const float4*)(wd + 32 + k);
        float4 wc = *(const float4*)(wd + 64 + k);
        float4 bv = *(const float4*)(wd + 96 + k);
#pragma unroll
        for (int c = 0; c < 4; ++c) {
            h1[c][k + 0] = fmaxf(0.f, x0[c] * wa.x + x1[c] * wb.x + x2[c] * wc.x + bv.x);
            h1[c][k + 1] = fmaxf(0.f, x0[c] * wa.y + x1[c] * wb.y + x2[c] * wc.y + bv.y);
            h1[c][k + 2] = fmaxf(0.f, x0[c] * wa.z + x1[c] * wb.z + x2[c] * wc.z + bv.z);
            h1[c][k + 3] = fmaxf(0.f, x0[c] * wa.w + x1[c] * wb.w + x2[c] * wc.w + bv.w);
        }
    }

    float acc[4];
    float b3v = wd[1216];
#pragma unroll
    for (int c = 0; c < 4; ++c) acc[c] = b3v;
#pragma unroll 1
    for (int k = 0; k < 32; k += 4) {
        float4 hb = *(const float4*)(wd + 1152 + k);
        float v[4][4];
#pragma unroll
        for (int c = 0; c < 4; ++c) {
            v[c][0] = hb.x; v[c][1] = hb.y; v[c][2] = hb.z; v[c][3] = hb.w;
        }
#pragma unroll
        for (int j = 0; j < 32; ++j) {
            float4 w2v = *(const float4*)(wd + 128 + j * 32 + k);
#pragma unroll
            for (int c = 0; c < 4; ++c) {
                v[c][0] += h1[c][j] * w2v.x;
                v[c][1] += h1[c][j] * w2v.y;
                v[c][2] += h1[c][j] * w2v.z;
                v[c][3] += h1[c][j] * w2v.w;
            }
        }
        float4 w3v = *(const float4*)(wd + 1184 + k);
#pragma unroll
        for (int c = 0; c < 4; ++c) {
            acc[c] += fmaxf(0.f, v[c][0]) * w3v.x + fmaxf(0.f, v[c][1]) * w3v.y +
                      fmaxf(0.f, v[c][2]) * w3v.z + fmaxf(0.f, v[c][3]) * w3v.w;
        }
    }
#pragma unroll
    for (int c = 0; c < 4; ++c)
        out[(size_t)(b0 + c * 32) * NG + gg] = acc[c];
}

extern "C" void kernel_launch(void* const* d_in, const int* in_sizes, int n_in,
                              void* d_out, int out_size, void* d_ws, size_t ws_size,
                              hipStream_t stream) {
    const float* data = (const float*)d_in[0];
    const float* A    = (const float*)d_in[1];
    const float* W1   = (const float*)d_in[2];
    const float* b1   = (const float*)d_in[3];
    const float* W2   = (const float*)d_in[4];
    const float* b2   = (const float*)d_in[5];
    const float* W3   = (const float*)d_in[6];
    const float* b3   = (const float*)d_in[7];
    float* out = (float*)d_out;
    float* ws = (float*)d_ws;

    float* D  = ws;
    float* P0 = ws + 524288;    // becomes S
    float* P1 = ws + 1048576;   // becomes M
    float* P2 = ws + 1572864;
    float* P3 = ws + 2097152;
    float* T1 = ws + 2621440;
    float* T2 = ws + 2883584;
    float* gA = ws + 3145728;
    float* gB = ws + 3407872;

    k_init<<<dim3(1024), dim3(256), 0, stream>>>(gA);
    k_D<<<dim3(128), dim3(256), 0, stream>>>(data, D);

    float* gc = gA;
    float* gn = gB;
    for (int it = 0; it < 3; ++it) {
        k_cov<<<dim3(512), dim3(256), 0, stream>>>(A, gc, P0, P1, P2, P3);
        k_invpost<<<dim3(128), dim3(256), 0, stream>>>(P0, P1, P2, P3, D, P0, P1);
        k_feat<<<dim3(1024), dim3(256), 0, stream>>>(A, P0, P1, T1, T2);
        float* dst = (it == 2) ? out : gn;
        k_mlp<<<dim3(256), dim3(256), 0, stream>>>(T1, T2, gc, W1, b1, W2, b2, W3, b3, it, dst);
        float* tmp = gc; gc = gn; gn = tmp;
    }
}